// Round 1
// 354.762 us; speedup vs baseline: 1.0063x; 1.0063x over previous
//
#include <hip/hip_runtime.h>
#include <hip/hip_bf16.h>
#include <cstdint>
#include <cstddef>

#define BB 8
#define TT 2048
#define CC 2048
#define EE 32
#define HH 64
#define NCH 64   // convsum chunks along T

typedef __bf16 v8bf __attribute__((ext_vector_type(8)));
typedef float v4f __attribute__((ext_vector_type(4)));

// async global->LDS, 16B per lane; LDS dest must be wave-uniform base (+lane*16 by HW)
#define GLOAD16(gp, lp)                                                              \
  __builtin_amdgcn_global_load_lds((const __attribute__((address_space(1))) void*)(gp), \
                                   (__attribute__((address_space(3))) void*)(lp), 16, 0, 0)

// ---------------- kernel 1: token partial sums + bf16 conversion (one pass over hs) ----
// grid (B*C/1024, NCH), block 256. float4 loads (16B/lane), ushort4 bf16 stores (8B/lane).
// 1024 blocks -> 4 waves/SIMD; unroll 8 keeps ~8 outstanding 16B loads per lane.
__global__ void k_convsum(const float* __restrict__ hs, __hip_bfloat16* __restrict__ hsb,
                          float* __restrict__ partial) {
    int idx4 = blockIdx.x * 256 + threadIdx.x;       // 0 .. B*C/4-1
    int chunk = blockIdx.y;
    int b = idx4 >> 9;                               // C/4 = 512 float4 per b
    int c4 = (idx4 & 511) * 4;
    const int ROWS = TT / NCH;                       // 32 rows per chunk
    const float4* p = (const float4*)(hs + (size_t)b * TT * CC + (size_t)chunk * ROWS * CC + c4);
    ushort4* q = (ushort4*)(hsb + (size_t)b * TT * CC + (size_t)chunk * ROWS * CC + c4);
    float4 s = {0.f, 0.f, 0.f, 0.f};
    #pragma unroll 8
    for (int t = 0; t < ROWS; ++t) {
        float4 v = p[(size_t)t * (CC / 4)];
        s.x += v.x; s.y += v.y; s.z += v.z; s.w += v.w;
        __hip_bfloat16 ob[4];
        ob[0] = __float2bfloat16(v.x); ob[1] = __float2bfloat16(v.y);
        ob[2] = __float2bfloat16(v.z); ob[3] = __float2bfloat16(v.w);
        q[(size_t)t * (CC / 4)] = *(const ushort4*)ob;
    }
    ((float4*)partial)[(size_t)chunk * (BB * CC / 4) + idx4] = s;
}

// ---------------- kernel 1b: collapse NCH chunk partials -> seq_rep (B,C) ----------------
// grid (B*C/1024), block 256. 4 MB read, 64 KB write.
__global__ void k_sumred(const float* __restrict__ partial, float* __restrict__ seqrep) {
    int idx4 = blockIdx.x * 256 + threadIdx.x;       // float4 index
    float4 s = {0.f, 0.f, 0.f, 0.f};
    #pragma unroll 8
    for (int ch = 0; ch < NCH; ++ch) {
        float4 v = ((const float4*)partial)[(size_t)ch * (BB * CC / 4) + idx4];
        s.x += v.x; s.y += v.y; s.z += v.z; s.w += v.w;
    }
    ((float4*)seqrep)[idx4] = s;
}

// ---------------- kernel 2: affinity logits, one block per (e,b) ----------------
// note: 1/T mean factor cancels in the cosine normalization -> skipped
__global__ void k_affinity(const float* __restrict__ seqrep, const float* __restrict__ sim,
                           const float* __restrict__ gates, float* __restrict__ logits) {
    __shared__ float red[256];
    int e = blockIdx.x, b = blockIdx.y, tid = threadIdx.x;
    float d = 0.f, n = 0.f, m2 = 0.f;
    for (int c = tid; c < CC; c += 256) {
        float sr = seqrep[b * CC + c];
        float sv = sim[(size_t)c * EE + e];
        d += sr * sv; n += sv * sv; m2 += sr * sr;
    }
    red[tid] = d; __syncthreads();
    for (int s = 128; s > 0; s >>= 1) { if (tid < s) red[tid] += red[tid + s]; __syncthreads(); }
    d = red[0]; __syncthreads();
    red[tid] = n; __syncthreads();
    for (int s = 128; s > 0; s >>= 1) { if (tid < s) red[tid] += red[tid + s]; __syncthreads(); }
    n = red[0]; __syncthreads();
    red[tid] = m2; __syncthreads();
    for (int s = 128; s > 0; s >>= 1) { if (tid < s) red[tid] += red[tid + s]; __syncthreads(); }
    m2 = red[0];
    if (tid == 0) {
        float aff = d * rsqrtf(n) * rsqrtf(m2);
        float sg = 1.0f / (1.0f + expf(-gates[e]));
        logits[b * EE + e] = aff - sg;
    }
}

// ---------------- kernel 3: mask/fallback/softmax -> routing (B,E) ----------------
__global__ void k_route(const float* __restrict__ logits, float* __restrict__ routing) {
    int b = threadIdx.x;
    if (b >= BB) return;
    float lg[EE], gated[EE];
    int mask[EE];
    int nact = 0;
    for (int e = 0; e < EE; ++e) {
        lg[e] = logits[b * EE + e];
        float g = lg[e] > 0.f ? lg[e] : 0.f;
        gated[e] = g;
        mask[e] = (g > 0.f) ? 1 : 0;
        nact += mask[e];
    }
    if (nact == 0) {
        int chosen[EE];
        for (int e = 0; e < EE; ++e) chosen[e] = 0;
        for (int k = 0; k < EE / 2; ++k) {   // stable top-k: strict > keeps lowest index on ties
            int best = -1; float bv = 0.f;
            for (int e = 0; e < EE; ++e) {
                if (chosen[e]) continue;
                if (best < 0 || lg[e] > bv) { best = e; bv = lg[e]; }
            }
            chosen[best] = 1;
        }
        for (int e = 0; e < EE; ++e) mask[e] = chosen[e];
    }
    float m = -3.402823466e+38f;
    for (int e = 0; e < EE; ++e)
        if (mask[e] && gated[e] > m) m = gated[e];
    float ssum = 0.f; float ex[EE];
    for (int e = 0; e < EE; ++e) {
        float v = mask[e] ? expf(gated[e] - m) : 0.f;
        ex[e] = v; ssum += v;
    }
    float inv = 1.0f / ssum;
    for (int e = 0; e < EE; ++e) routing[b * EE + e] = ex[e] * inv;
}

// ---------------- kernel 4: routing-weighted weight mix -> bf16 ----------------
// grid (H*C/256, 2), block 256. y==0 -> w_v_eff, y==1 -> w_o_dyn
__global__ void k_wmix(const float* __restrict__ w_v, const float* __restrict__ o_w,
                       const float* __restrict__ routing,
                       __hip_bfloat16* __restrict__ wv_eff, __hip_bfloat16* __restrict__ wo_eff) {
    __shared__ float r[BB * EE];
    int tid = threadIdx.x;
    r[tid] = routing[tid];          // BB*EE == 256 == blockDim
    __syncthreads();
    size_t idx = (size_t)blockIdx.x * 256 + tid;
    const float* w = blockIdx.y ? o_w : w_v;
    __hip_bfloat16* dst = blockIdx.y ? wo_eff : wv_eff;
    float acc[BB] = {};
    for (int e = 0; e < EE; ++e) {
        float v = w[(size_t)e * HH * CC + idx];
        #pragma unroll
        for (int b = 0; b < BB; ++b) acc[b] += r[b * EE + e] * v;
    }
    #pragma unroll
    for (int b = 0; b < BB; ++b) dst[(size_t)b * HH * CC + idx] = __float2bfloat16(acc[b]);
}

// ---------------- kernel 5: GEMM1 bf16 MFMA: partialC[kc] = hs_bf16 @ w_v_eff^T ----------
// grid (T/64, 4, B), block 256. NT layout: both A and B rows are [row][K] contiguous.
// XOR swizzle: chunk (row, c) of a 64-row x 64-col bf16 tile lives at LDS slot
// row*8 + (c ^ (row&7)) (16B chunks) -> conflict-free ds_read_b128 at BK=64 while
// satisfying global_load_lds's linear lane->LDS constraint.
// Split-K=4 (was 2): 1024 blocks -> 4 waves/SIMD to hide the per-iter vmcnt(0) drain.
__global__ __launch_bounds__(256) void k_gemm1(const __hip_bfloat16* __restrict__ A,
                                               const __hip_bfloat16* __restrict__ Bw,
                                               float* __restrict__ partialC) {
    __shared__ __align__(16) __hip_bfloat16 Asm[64 * 64];
    __shared__ __align__(16) __hip_bfloat16 Bsm[64 * 64];
    int tid = threadIdx.x;
    int t0 = blockIdx.x * 64;
    int kc = blockIdx.y;
    int b  = blockIdx.z;
    const __hip_bfloat16* Ag = A + (size_t)b * TT * CC + (size_t)t0 * CC;
    const __hip_bfloat16* Bg = Bw + (size_t)b * HH * CC;
    int wv = tid >> 6, lane = tid & 63, lm = lane & 15, quad = lane >> 4;
    int L0 = tid, L1 = tid + 256;
    int row0 = L0 >> 3, c0 = ((L0 & 7) ^ (row0 & 7)) * 8;
    int row1 = L1 >> 3, c1 = ((L1 & 7) ^ (row1 & 7)) * 8;
    char* AsmB = (char*)Asm;
    char* BsmB = (char*)Bsm;
    int ldsoff0 = (wv * 64 + lane) * 16;        // == L0*16, wave-uniform base + lane*16
    int ldsoff1 = (256 + wv * 64 + lane) * 16;  // == L1*16
    v4f acc[4] = {};
    int kend = kc * (CC / 4) + CC / 4;
    for (int kk0 = kc * (CC / 4); kk0 < kend; kk0 += 64) {
        GLOAD16(Ag + (size_t)row0 * CC + kk0 + c0, AsmB + ldsoff0);
        GLOAD16(Ag + (size_t)row1 * CC + kk0 + c1, AsmB + ldsoff1);
        GLOAD16(Bg + (size_t)row0 * CC + kk0 + c0, BsmB + ldsoff0);
        GLOAD16(Bg + (size_t)row1 * CC + kk0 + c1, BsmB + ldsoff1);
        __syncthreads();
        int arow = wv * 16 + lm;
        #pragma unroll
        for (int s = 0; s < 2; ++s) {
            v8bf a = *(const v8bf*)(AsmB + (arow * 8 + ((s * 4 + quad) ^ (arow & 7))) * 16);
            #pragma unroll
            for (int j = 0; j < 4; ++j) {
                int brow = j * 16 + lm;
                v8bf bb = *(const v8bf*)(BsmB + (brow * 8 + ((s * 4 + quad) ^ (brow & 7))) * 16);
                acc[j] = __builtin_amdgcn_mfma_f32_16x16x32_bf16(a, bb, acc[j], 0, 0, 0);
            }
        }
        __syncthreads();
    }
    float* Cp = partialC + ((size_t)kc * BB + b) * TT * HH + (size_t)t0 * HH;
    #pragma unroll
    for (int j = 0; j < 4; ++j)
        #pragma unroll
        for (int r2 = 0; r2 < 4; ++r2)
            Cp[(size_t)(wv * 16 + quad * 4 + r2) * HH + j * 16 + lm] = acc[j][r2];
}

// ---------------- kernel 6: split-K reduce (4 slices) -> combined bf16 ----------------
__global__ void k_reduce(const float* __restrict__ pC, __hip_bfloat16* __restrict__ comb) {
    size_t i = (size_t)blockIdx.x * 256 + threadIdx.x;
    const size_t N = (size_t)BB * TT * HH;
    comb[i] = __float2bfloat16(pC[i] + pC[i + N] + pC[i + 2 * N] + pC[i + 3 * N]);
}

// ---------------- kernel 7: GEMM2 bf16 MFMA: out = combined @ w_o_dyn ----------------
// grid (C/64, T/64, B), block 256. K=64 single-shot; B staged transposed with pad 72.
__global__ __launch_bounds__(256) void k_gemm2(const __hip_bfloat16* __restrict__ comb,
                                               const __hip_bfloat16* __restrict__ Wo,
                                               float* __restrict__ out) {
    __shared__ __align__(16) __hip_bfloat16 As[64 * 72];
    __shared__ __align__(16) __hip_bfloat16 Bs[64 * 72];
    int tid = threadIdx.x;
    int d0 = blockIdx.x * 64, t0 = blockIdx.y * 64, b = blockIdx.z;
    const __hip_bfloat16* Ag = comb + (size_t)b * TT * HH + (size_t)t0 * HH;
    const __hip_bfloat16* Bg = Wo + (size_t)b * HH * CC + d0;
    #pragma unroll
    for (int r = 0; r < 2; ++r) {              // A tile: [t][h] rows contiguous
        int L = tid + r * 256;
        int row = L >> 3, c = (L & 7) * 8;
        *(int4*)&As[row * 72 + c] = *(const int4*)&Ag[row * 64 + c];
    }
    #pragma unroll
    for (int i = 0; i < 16; ++i) {             // B tile transposed: Bs[d][h] = Wo[h][d0+d]
        int e2 = tid + i * 256;
        int h = e2 >> 6, d = e2 & 63;
        Bs[d * 72 + h] = Bg[(size_t)h * CC + d];
    }
    __syncthreads();
    int wv = tid >> 6, lane = tid & 63, lm = lane & 15, quad = lane >> 4;
    v4f acc[4] = {};
    #pragma unroll
    for (int s = 0; s < 2; ++s) {
        v8bf a = *(const v8bf*)&As[(wv * 16 + lm) * 72 + s * 32 + quad * 8];
        #pragma unroll
        for (int j = 0; j < 4; ++j) {
            v8bf bb = *(const v8bf*)&Bs[(j * 16 + lm) * 72 + s * 32 + quad * 8];
            acc[j] = __builtin_amdgcn_mfma_f32_16x16x32_bf16(a, bb, acc[j], 0, 0, 0);
        }
    }
    float* Og = out + (size_t)b * TT * CC + (size_t)t0 * CC + d0;
    #pragma unroll
    for (int j = 0; j < 4; ++j)
        #pragma unroll
        for (int r2 = 0; r2 < 4; ++r2)
            Og[(size_t)(wv * 16 + quad * 4 + r2) * CC + j * 16 + lm] = acc[j][r2];
}

extern "C" void kernel_launch(void* const* d_in, const int* in_sizes, int n_in,
                              void* d_out, int out_size, void* d_ws, size_t ws_size,
                              hipStream_t stream) {
    const float* hs    = (const float*)d_in[0];   // (B,T,C)
    const float* sim   = (const float*)d_in[1];   // (C,E)
    const float* gates = (const float*)d_in[2];   // (E,)
    // d_in[3]=w_q, d_in[4]=w_k: dead (seq_len-1 SDPA == identity on v)
    const float* w_v   = (const float*)d_in[5];   // (E,H,C)
    const float* o_w   = (const float*)d_in[6];   // (E,H,C)
    float* out = (float*)d_out;
    float* ws  = (float*)d_ws;

    // workspace layout (float units)
    size_t o = 0;
    float* partial = ws + o;                         o += (size_t)NCH * BB * CC;     // 1048576
    float* seqrep  = ws + o;                         o += BB * CC;                   // 16384
    float* logits  = ws + o;                         o += BB * EE;                   // 256
    float* routing = ws + o;                         o += BB * EE;                   // 256
    float* partialC = ws + o;                        o += (size_t)4 * BB * TT * HH;  // 4194304
    __hip_bfloat16* comb = (__hip_bfloat16*)(ws + o); o += (size_t)BB * TT * HH / 2;
    __hip_bfloat16* wve  = (__hip_bfloat16*)(ws + o); o += (size_t)BB * HH * CC / 2;
    __hip_bfloat16* woe  = (__hip_bfloat16*)(ws + o); o += (size_t)BB * HH * CC / 2;
    size_t f_hsb = (size_t)BB * TT * CC / 2;         // 67 MB as floats/2
    bool big = ws_size >= (o + f_hsb) * sizeof(float);
    // small-ws fallback: hs_bf16 overlays the front of d_out (67 of 134 MB);
    // safe because k_gemm2 never reads d_out and fully overwrites it at the end.
    __hip_bfloat16* hsb = big ? (__hip_bfloat16*)(ws + o) : (__hip_bfloat16*)d_out;

    hipLaunchKernelGGL(k_convsum, dim3(BB * CC / 1024, NCH), dim3(256), 0, stream,
                       hs, hsb, partial);
    hipLaunchKernelGGL(k_sumred, dim3(BB * CC / 1024), dim3(256), 0, stream,
                       partial, seqrep);
    hipLaunchKernelGGL(k_affinity, dim3(EE, BB), dim3(256), 0, stream,
                       seqrep, sim, gates, logits);
    hipLaunchKernelGGL(k_route, dim3(1), dim3(64), 0, stream, logits, routing);
    hipLaunchKernelGGL(k_wmix, dim3(HH * CC / 256, 2), dim3(256), 0, stream,
                       w_v, o_w, routing, wve, woe);
    hipLaunchKernelGGL(k_gemm1, dim3(TT / 64, 4, BB), dim3(256), 0, stream,
                       hsb, wve, partialC);
    hipLaunchKernelGGL(k_reduce, dim3(BB * TT * HH / 256), dim3(256), 0, stream,
                       partialC, comb);
    hipLaunchKernelGGL(k_gemm2, dim3(CC / 64, TT / 64, BB), dim3(256), 0, stream,
                       comb, woe, out);
}

// Round 2
// 325.396 us; speedup vs baseline: 1.0971x; 1.0902x over previous
//
#include <hip/hip_runtime.h>
#include <hip/hip_bf16.h>
#include <cstdint>
#include <cstddef>

#define BB 8
#define TT 2048
#define CC 2048
#define EE 32
#define HH 64
#define NCH 64   // convsum chunks along T

typedef __bf16 v8bf __attribute__((ext_vector_type(8)));
typedef float v4f __attribute__((ext_vector_type(4)));

// async global->LDS, 16B per lane; LDS dest must be wave-uniform base (+lane*16 by HW)
#define GLOAD16(gp, lp)                                                              \
  __builtin_amdgcn_global_load_lds((const __attribute__((address_space(1))) void*)(gp), \
                                   (__attribute__((address_space(3))) void*)(lp), 16, 0, 0)

// ---------------- kernel 1: token partial sums (read-only pass over hs) ----------------
// grid (B*C/1024, NCH), block 256. float4 loads, 16B/lane. No bf16 copy anymore:
// GEMM1 reads hs fp32 straight from L3 (hs is L3-resident after this pass).
__global__ void k_convsum(const float* __restrict__ hs, float* __restrict__ partial) {
    int idx4 = blockIdx.x * 256 + threadIdx.x;       // 0 .. B*C/4-1
    int chunk = blockIdx.y;
    int b = idx4 >> 9;                               // C/4 = 512 float4 per b
    int c4 = (idx4 & 511) * 4;
    const int ROWS = TT / NCH;                       // 32 rows per chunk
    const float4* p = (const float4*)(hs + (size_t)b * TT * CC + (size_t)chunk * ROWS * CC + c4);
    float4 s = {0.f, 0.f, 0.f, 0.f};
    #pragma unroll 8
    for (int t = 0; t < ROWS; ++t) {
        float4 v = p[(size_t)t * (CC / 4)];
        s.x += v.x; s.y += v.y; s.z += v.z; s.w += v.w;
    }
    ((float4*)partial)[(size_t)chunk * (BB * CC / 4) + idx4] = s;
}

// ---------------- kernel 1b: collapse NCH chunk partials -> seq_rep (B,C) ----------------
__global__ void k_sumred(const float* __restrict__ partial, float* __restrict__ seqrep) {
    int idx4 = blockIdx.x * 256 + threadIdx.x;       // float4 index
    float4 s = {0.f, 0.f, 0.f, 0.f};
    #pragma unroll 8
    for (int ch = 0; ch < NCH; ++ch) {
        float4 v = ((const float4*)partial)[(size_t)ch * (BB * CC / 4) + idx4];
        s.x += v.x; s.y += v.y; s.z += v.z; s.w += v.w;
    }
    ((float4*)seqrep)[idx4] = s;
}

// ---------------- kernel 2: affinity logits, one block per (e,b) ----------------
// note: 1/T mean factor cancels in the cosine normalization -> skipped
__global__ void k_affinity(const float* __restrict__ seqrep, const float* __restrict__ sim,
                           const float* __restrict__ gates, float* __restrict__ logits) {
    __shared__ float red[256];
    int e = blockIdx.x, b = blockIdx.y, tid = threadIdx.x;
    float d = 0.f, n = 0.f, m2 = 0.f;
    for (int c = tid; c < CC; c += 256) {
        float sr = seqrep[b * CC + c];
        float sv = sim[(size_t)c * EE + e];
        d += sr * sv; n += sv * sv; m2 += sr * sr;
    }
    red[tid] = d; __syncthreads();
    for (int s = 128; s > 0; s >>= 1) { if (tid < s) red[tid] += red[tid + s]; __syncthreads(); }
    d = red[0]; __syncthreads();
    red[tid] = n; __syncthreads();
    for (int s = 128; s > 0; s >>= 1) { if (tid < s) red[tid] += red[tid + s]; __syncthreads(); }
    n = red[0]; __syncthreads();
    red[tid] = m2; __syncthreads();
    for (int s = 128; s > 0; s >>= 1) { if (tid < s) red[tid] += red[tid + s]; __syncthreads(); }
    m2 = red[0];
    if (tid == 0) {
        float aff = d * rsqrtf(n) * rsqrtf(m2);
        float sg = 1.0f / (1.0f + expf(-gates[e]));
        logits[b * EE + e] = aff - sg;
    }
}

// ---------------- kernel 3: routing + weight mix fused ----------------
// grid (H*C/256, 2), block 256. y==0 -> w_v_eff, y==1 -> w_o_dyn.
// Routing computed wave-parallel per block from logits: thread tid = b*32+e.
// Fallback top-16 via stable shuffle-rank (ties -> lowest e, matches lax.top_k).
__global__ void k_wmix(const float* __restrict__ w_v, const float* __restrict__ o_w,
                       const float* __restrict__ logits,
                       __hip_bfloat16* __restrict__ wv_eff, __hip_bfloat16* __restrict__ wo_eff) {
    __shared__ float r[BB * EE];
    int tid = threadIdx.x;
    int lane = tid & 63;
    int sub = lane & 31;                 // e within 32-lane expert group
    float lg = logits[tid];              // BB*EE == 256 == blockDim
    float gated = lg > 0.f ? lg : 0.f;
    bool act = gated > 0.f;
    unsigned long long bal = __ballot(act);
    unsigned halfmask = (lane & 32) ? (unsigned)(bal >> 32) : (unsigned)bal;
    bool sel;
    if (__popc(halfmask) == 0) {
        // fallback: top-(E/2) by raw logits within this sequence's 32-lane group
        int base = lane & 32;
        int rank = 0;
        #pragma unroll
        for (int j = 0; j < EE; ++j) {
            float lj = __shfl(lg, base + j, 64);
            rank += (lj > lg) || (lj == lg && j < sub);
        }
        sel = rank < (EE / 2);
    } else {
        sel = act;
    }
    float mv = sel ? gated : -3.402823466e+38f;
    #pragma unroll
    for (int k = 16; k >= 1; k >>= 1) mv = fmaxf(mv, __shfl_xor(mv, k, 64));
    float ex = sel ? expf(gated - mv) : 0.f;
    float ss = ex;
    #pragma unroll
    for (int k = 16; k >= 1; k >>= 1) ss += __shfl_xor(ss, k, 64);
    r[tid] = ex / ss;
    __syncthreads();

    size_t idx = (size_t)blockIdx.x * 256 + tid;
    const float* w = blockIdx.y ? o_w : w_v;
    __hip_bfloat16* dst = blockIdx.y ? wo_eff : wv_eff;
    float acc[BB] = {};
    for (int e = 0; e < EE; ++e) {
        float v = w[(size_t)e * HH * CC + idx];
        #pragma unroll
        for (int b = 0; b < BB; ++b) acc[b] += r[b * EE + e] * v;
    }
    #pragma unroll
    for (int b = 0; b < BB; ++b) dst[(size_t)b * HH * CC + idx] = __float2bfloat16(acc[b]);
}

// ---------------- kernel 4: GEMM1 bf16 MFMA: partialC[kc] = cvt(hs_f32) @ w_v_eff^T -----
// grid (T/64, 4, B), block 256. A is read fp32 from L3 and converted in-kernel during
// reg-staged LDS writes (ds_write side computes the XOR swizzle; read side unchanged).
// B (wve, bf16) stays async global_load_lds with pre-swizzled global source.
// LDS chunk layout: chunk (row, c) of the 64x64 bf16 tile at slot row*8 + (c ^ (row&7)).
__global__ __launch_bounds__(256) void k_gemm1(const float* __restrict__ A,
                                               const __hip_bfloat16* __restrict__ Bw,
                                               float* __restrict__ partialC) {
    __shared__ __align__(16) __hip_bfloat16 Asm[64 * 64];
    __shared__ __align__(16) __hip_bfloat16 Bsm[64 * 64];
    int tid = threadIdx.x;
    int t0 = blockIdx.x * 64;
    int kc = blockIdx.y;
    int b  = blockIdx.z;
    const __hip_bfloat16* Bg = Bw + (size_t)b * HH * CC;
    int wv = tid >> 6, lane = tid & 63, lm = lane & 15, quad = lane >> 4;
    int L0 = tid, L1 = tid + 256;
    int row0 = L0 >> 3, c0 = ((L0 & 7) ^ (row0 & 7)) * 8;
    int row1 = L1 >> 3, c1 = ((L1 & 7) ^ (row1 & 7)) * 8;
    char* AsmB = (char*)Asm;
    char* BsmB = (char*)Bsm;
    int ldsoff0 = (wv * 64 + lane) * 16;        // == L0*16, wave-uniform base + lane*16
    int ldsoff1 = (256 + wv * 64 + lane) * 16;  // == L1*16
    // A reg-stage mapping: thread -> (row ar, 16-float group aq) = 2 bf16 chunks
    int ar = tid >> 2;                          // 0..63
    int aq = tid & 3;                           // 0..3
    const float* Ag = A + ((size_t)b * TT + t0 + ar) * CC + aq * 16;
    int as0 = (ar * 8 + ((2 * aq) ^ (ar & 7))) * 16;
    int as1 = (ar * 8 + ((2 * aq + 1) ^ (ar & 7))) * 16;
    v4f acc[4] = {};
    int kend = kc * (CC / 4) + CC / 4;
    for (int kk0 = kc * (CC / 4); kk0 < kend; kk0 += 64) {
        GLOAD16(Bg + (size_t)row0 * CC + kk0 + c0, BsmB + ldsoff0);
        GLOAD16(Bg + (size_t)row1 * CC + kk0 + c1, BsmB + ldsoff1);
        float4 f0 = *(const float4*)(Ag + kk0);
        float4 f1 = *(const float4*)(Ag + kk0 + 4);
        float4 f2 = *(const float4*)(Ag + kk0 + 8);
        float4 f3 = *(const float4*)(Ag + kk0 + 12);
        union { v8bf v; __hip_bfloat16 h[8]; } u0, u1;
        u0.h[0] = __float2bfloat16(f0.x); u0.h[1] = __float2bfloat16(f0.y);
        u0.h[2] = __float2bfloat16(f0.z); u0.h[3] = __float2bfloat16(f0.w);
        u0.h[4] = __float2bfloat16(f1.x); u0.h[5] = __float2bfloat16(f1.y);
        u0.h[6] = __float2bfloat16(f1.z); u0.h[7] = __float2bfloat16(f1.w);
        u1.h[0] = __float2bfloat16(f2.x); u1.h[1] = __float2bfloat16(f2.y);
        u1.h[2] = __float2bfloat16(f2.z); u1.h[3] = __float2bfloat16(f2.w);
        u1.h[4] = __float2bfloat16(f3.x); u1.h[5] = __float2bfloat16(f3.y);
        u1.h[6] = __float2bfloat16(f3.z); u1.h[7] = __float2bfloat16(f3.w);
        *(v8bf*)(AsmB + as0) = u0.v;
        *(v8bf*)(AsmB + as1) = u1.v;
        __syncthreads();
        int arow = wv * 16 + lm;
        #pragma unroll
        for (int s = 0; s < 2; ++s) {
            v8bf a = *(const v8bf*)(AsmB + (arow * 8 + ((s * 4 + quad) ^ (arow & 7))) * 16);
            #pragma unroll
            for (int j = 0; j < 4; ++j) {
                int brow = j * 16 + lm;
                v8bf bb = *(const v8bf*)(BsmB + (brow * 8 + ((s * 4 + quad) ^ (brow & 7))) * 16);
                acc[j] = __builtin_amdgcn_mfma_f32_16x16x32_bf16(a, bb, acc[j], 0, 0, 0);
            }
        }
        __syncthreads();
    }
    float* Cp = partialC + ((size_t)kc * BB + b) * TT * HH + (size_t)t0 * HH;
    #pragma unroll
    for (int j = 0; j < 4; ++j)
        #pragma unroll
        for (int r2 = 0; r2 < 4; ++r2)
            Cp[(size_t)(wv * 16 + quad * 4 + r2) * HH + j * 16 + lm] = acc[j][r2];
}

// ---------------- kernel 5: split-K reduce (4 slices) -> combined bf16 ----------------
__global__ void k_reduce(const float* __restrict__ pC, __hip_bfloat16* __restrict__ comb) {
    size_t i = (size_t)blockIdx.x * 256 + threadIdx.x;
    const size_t N = (size_t)BB * TT * HH;
    comb[i] = __float2bfloat16(pC[i] + pC[i + N] + pC[i + 2 * N] + pC[i + 3 * N]);
}

// ---------------- kernel 6: GEMM2 bf16 MFMA: out = combined @ w_o_dyn ----------------
// grid (C/64, T/64, B), block 256. K=64 single-shot; B staged transposed with pad 72.
__global__ __launch_bounds__(256) void k_gemm2(const __hip_bfloat16* __restrict__ comb,
                                               const __hip_bfloat16* __restrict__ Wo,
                                               float* __restrict__ out) {
    __shared__ __align__(16) __hip_bfloat16 As[64 * 72];
    __shared__ __align__(16) __hip_bfloat16 Bs[64 * 72];
    int tid = threadIdx.x;
    int d0 = blockIdx.x * 64, t0 = blockIdx.y * 64, b = blockIdx.z;
    const __hip_bfloat16* Ag = comb + (size_t)b * TT * HH + (size_t)t0 * HH;
    const __hip_bfloat16* Bg = Wo + (size_t)b * HH * CC + d0;
    #pragma unroll
    for (int r = 0; r < 2; ++r) {              // A tile: [t][h] rows contiguous
        int L = tid + r * 256;
        int row = L >> 3, c = (L & 7) * 8;
        *(int4*)&As[row * 72 + c] = *(const int4*)&Ag[row * 64 + c];
    }
    #pragma unroll
    for (int i = 0; i < 16; ++i) {             // B tile transposed: Bs[d][h] = Wo[h][d0+d]
        int e2 = tid + i * 256;
        int h = e2 >> 6, d = e2 & 63;
        Bs[d * 72 + h] = Bg[(size_t)h * CC + d];
    }
    __syncthreads();
    int wv = tid >> 6, lane = tid & 63, lm = lane & 15, quad = lane >> 4;
    v4f acc[4] = {};
    #pragma unroll
    for (int s = 0; s < 2; ++s) {
        v8bf a = *(const v8bf*)&As[(wv * 16 + lm) * 72 + s * 32 + quad * 8];
        #pragma unroll
        for (int j = 0; j < 4; ++j) {
            v8bf bb = *(const v8bf*)&Bs[(j * 16 + lm) * 72 + s * 32 + quad * 8];
            acc[j] = __builtin_amdgcn_mfma_f32_16x16x32_bf16(a, bb, acc[j], 0, 0, 0);
        }
    }
    float* Og = out + (size_t)b * TT * CC + (size_t)t0 * CC + d0;
    #pragma unroll
    for (int j = 0; j < 4; ++j)
        #pragma unroll
        for (int r2 = 0; r2 < 4; ++r2)
            Og[(size_t)(wv * 16 + quad * 4 + r2) * CC + j * 16 + lm] = acc[j][r2];
}

extern "C" void kernel_launch(void* const* d_in, const int* in_sizes, int n_in,
                              void* d_out, int out_size, void* d_ws, size_t ws_size,
                              hipStream_t stream) {
    const float* hs    = (const float*)d_in[0];   // (B,T,C)
    const float* sim   = (const float*)d_in[1];   // (C,E)
    const float* gates = (const float*)d_in[2];   // (E,)
    // d_in[3]=w_q, d_in[4]=w_k: dead (seq_len-1 SDPA == identity on v)
    const float* w_v   = (const float*)d_in[5];   // (E,H,C)
    const float* o_w   = (const float*)d_in[6];   // (E,H,C)
    float* out = (float*)d_out;
    float* ws  = (float*)d_ws;

    // workspace layout (float units)
    size_t o = 0;
    float* partial = ws + o;                         o += (size_t)NCH * BB * CC;     // 1048576
    float* seqrep  = ws + o;                         o += BB * CC;                   // 16384
    float* logits  = ws + o;                         o += BB * EE;                   // 256
    float* partialC = ws + o;                        o += (size_t)4 * BB * TT * HH;  // 4194304
    __hip_bfloat16* comb = (__hip_bfloat16*)(ws + o); o += (size_t)BB * TT * HH / 2;
    __hip_bfloat16* wve  = (__hip_bfloat16*)(ws + o); o += (size_t)BB * HH * CC / 2;
    __hip_bfloat16* woe  = (__hip_bfloat16*)(ws + o); o += (size_t)BB * HH * CC / 2;

    hipLaunchKernelGGL(k_convsum, dim3(BB * CC / 1024, NCH), dim3(256), 0, stream,
                       hs, partial);
    hipLaunchKernelGGL(k_sumred, dim3(BB * CC / 1024), dim3(256), 0, stream,
                       partial, seqrep);
    hipLaunchKernelGGL(k_affinity, dim3(EE, BB), dim3(256), 0, stream,
                       seqrep, sim, gates, logits);
    hipLaunchKernelGGL(k_wmix, dim3(HH * CC / 256, 2), dim3(256), 0, stream,
                       w_v, o_w, logits, wve, woe);
    hipLaunchKernelGGL(k_gemm1, dim3(TT / 64, 4, BB), dim3(256), 0, stream,
                       hs, wve, partialC);
    hipLaunchKernelGGL(k_reduce, dim3(BB * TT * HH / 256), dim3(256), 0, stream,
                       partialC, comb);
    hipLaunchKernelGGL(k_gemm2, dim3(CC / 64, TT / 64, BB), dim3(256), 0, stream,
                       comb, woe, out);
}